// Round 3
// baseline (186.112 us; speedup 1.0000x reference)
//
#include <hip/hip_runtime.h>
#include <math.h>

#define EPS_D 1e-6
#define SUB 256          // samples per sub-tile (== blockDim)
#define SPB (2 * SUB)    // samples per block

// Closed-form ortho term for one sample, no transcendentals beyond sqrt.
// lambda_min via monotone fixed point lam <- det(A)/q(lam) (fp64), then
// fp64 sqrt -> fp32 round -> +eps -> sum sigma^2 + sigma^-2. Numerics
// identical to the R2-passing kernel (absmax 24576).
__device__ __forceinline__ void sample_ortho(const float4 t0, const float4 t1,
                                             const float4 t2, double& ortho)
{
    double w00 = t0.x, w01 = t0.y, w02 = t0.z;
    double w10 = t1.x, w11 = t1.y, w12 = t1.z;
    double w20 = t2.x, w21 = t2.y, w22 = t2.z;

    // A = W^T W
    double A00 = w00*w00 + w10*w10 + w20*w20;
    double A11 = w01*w01 + w11*w11 + w21*w21;
    double A22 = w02*w02 + w12*w12 + w22*w22;
    double A01 = w00*w01 + w10*w11 + w20*w21;
    double A02 = w00*w02 + w10*w12 + w20*w22;
    double A12 = w01*w02 + w11*w12 + w21*w22;

    double I1 = A00 + A11 + A22;
    double I2 = (A00*A11 - A01*A01) + (A00*A22 - A02*A02) + (A11*A22 - A12*A12);
    double detW = w00*(w11*w22 - w12*w21)
                - w01*(w10*w22 - w12*w20)
                + w02*(w10*w21 - w11*w20);
    double I3 = detW * detW;   // = det(A) >= 0

    // Smallest eigenvalue: monotone fixed point, converges from below;
    // immediate for the near-singular samples that dominate the loss.
    double lam = (I2 > 0.0) ? I3 / I2 : 0.0;
    #pragma unroll
    for (int it = 0; it < 6; ++it) {
        double q = (lam - I1) * lam + I2;
        lam = (q > 0.0) ? I3 / q : lam;
    }
    if (lam < 0.0) lam = 0.0;

    // Remaining two eigenvalues from the deflated quadratic.
    double S = I1 - lam;
    double P = (lam - I1) * lam + I2;    // ~ lam1*lam2
    double disc = S * S - 4.0 * P;
    disc = (disc > 0.0) ? sqrt(disc) : 0.0;
    double l1 = 0.5 * (S + disc); if (l1 < 0.0) l1 = 0.0;
    double l2 = 0.5 * (S - disc); if (l2 < 0.0) l2 = 0.0;

    double s1 = (double)(float)sqrt(l1) + EPS_D;
    double s2 = (double)(float)sqrt(l2) + EPS_D;
    double s3 = (double)(float)sqrt(lam) + EPS_D;
    double q1 = s1 * s1, q2 = s2 * s2, q3 = s3 * s3;
    double inv = 1.0 / (q1 * q2 * q3);
    ortho += (q1 + q2 + q3) + inv * (q2 * q3 + q1 * q3 + q1 * q2) - 6.0;
}

__global__ __launch_bounds__(256) void theta_loss_fused(
    const float4* __restrict__ theta4,
    const float4* __restrict__ affine4,
    unsigned int* __restrict__ cnt,      // zeroed by hipMemsetAsync
    double* __restrict__ partial,
    float* __restrict__ out, int n)
{
    __shared__ float4 ldsA[3 * SUB];
    __shared__ float4 ldsB[3 * SUB];
    __shared__ double so[4], sm[4];
    __shared__ int lastFlag;

    const int t = threadIdx.x;
    const int blockSample = blockIdx.x * SPB;
    const int n4 = n * 3;
    double mse = 0.0, ortho = 0.0;

    // ---- stage sub-tile 0 (coalesced float4) + streaming MSE ----
    {
        int base4 = blockSample * 3;
        #pragma unroll
        for (int k = 0; k < 3; ++k) {
            int j = base4 + t + k * SUB;
            float4 tv = make_float4(0.f, 0.f, 0.f, 0.f);
            float4 av = make_float4(0.f, 0.f, 0.f, 0.f);
            if (j < n4) { tv = theta4[j]; av = affine4[j]; }
            float dx = tv.x - av.x, dy = tv.y - av.y;
            float dz = tv.z - av.z, dw = tv.w - av.w;
            mse += (double)(dx * dx + dy * dy) + (double)(dz * dz + dw * dw);
            ldsA[t + k * SUB] = tv;
        }
    }
    __syncthreads();

    // ---- issue sub-tile-1 global loads early (overlap with compute 0) ----
    float4 tvB[3], avB[3];
    {
        int base4 = (blockSample + SUB) * 3;
        #pragma unroll
        for (int k = 0; k < 3; ++k) {
            int j = base4 + t + k * SUB;
            tvB[k] = make_float4(0.f, 0.f, 0.f, 0.f);
            avB[k] = make_float4(0.f, 0.f, 0.f, 0.f);
            if (j < n4) { tvB[k] = theta4[j]; avB[k] = affine4[j]; }
        }
    }

    // ---- compute sub-tile 0 (stride-12-dword LDS reads: conflict-free) ----
    if (blockSample + t < n) {
        float4 a0 = ldsA[3 * t], a1 = ldsA[3 * t + 1], a2 = ldsA[3 * t + 2];
        sample_ortho(a0, a1, a2, ortho);
    }

    // ---- finish staging sub-tile 1 ----
    #pragma unroll
    for (int k = 0; k < 3; ++k) {
        float dx = tvB[k].x - avB[k].x, dy = tvB[k].y - avB[k].y;
        float dz = tvB[k].z - avB[k].z, dw = tvB[k].w - avB[k].w;
        mse += (double)(dx * dx + dy * dy) + (double)(dz * dz + dw * dw);
        ldsB[t + k * SUB] = tvB[k];
    }
    __syncthreads();

    // ---- compute sub-tile 1 ----
    if (blockSample + SUB + t < n) {
        float4 b0 = ldsB[3 * t], b1 = ldsB[3 * t + 1], b2 = ldsB[3 * t + 2];
        sample_ortho(b0, b1, b2, ortho);
    }

    // ---- block reduction: wave64 shuffle -> LDS ----
    #pragma unroll
    for (int off = 32; off > 0; off >>= 1) {
        ortho += __shfl_down(ortho, off);
        mse   += __shfl_down(mse, off);
    }
    int lane = t & 63, wv = t >> 6;
    if (lane == 0) { so[wv] = ortho; sm[wv] = mse; }
    __syncthreads();

    // ---- publish partial; last block reduces (retirement counter) ----
    if (t == 0) {
        partial[2 * blockIdx.x]     = so[0] + so[1] + so[2] + so[3];
        partial[2 * blockIdx.x + 1] = sm[0] + sm[1] + sm[2] + sm[3];
        __threadfence();                               // release partials
        unsigned int old = atomicAdd(cnt, 1u);         // device-scope
        lastFlag = (old == gridDim.x - 1) ? 1 : 0;
    }
    __syncthreads();

    if (lastFlag) {
        __threadfence();                               // acquire partials
        double O = 0.0, M = 0.0;
        for (int i = t; i < (int)gridDim.x; i += 256) {
            O += partial[2 * i];
            M += partial[2 * i + 1];
        }
        #pragma unroll
        for (int off = 32; off > 0; off >>= 1) {
            O += __shfl_down(O, off);
            M += __shfl_down(M, off);
        }
        if (lane == 0) { so[wv] = O; sm[wv] = M; }
        __syncthreads();
        if (t == 0) {
            double Ot = so[0] + so[1] + so[2] + so[3];
            double Mt = sm[0] + sm[1] + sm[2] + sm[3];
            out[0] = (float)(Ot / (double)n);
            out[1] = (float)(Mt / (12.0 * (double)n));
        }
    }
}

extern "C" void kernel_launch(void* const* d_in, const int* in_sizes, int n_in,
                              void* d_out, int out_size, void* d_ws, size_t ws_size,
                              hipStream_t stream) {
    const float4* theta4  = (const float4*)d_in[0];
    const float4* affine4 = (const float4*)d_in[1];
    unsigned int* cnt = (unsigned int*)d_ws;
    double* partial = (double*)((char*)d_ws + 256);
    float* out = (float*)d_out;
    int n = in_sizes[0] / 12;           // samples of 3x4

    hipMemsetAsync(cnt, 0, sizeof(unsigned int), stream);
    int blocks = (n + SPB - 1) / SPB;   // 2048 for n = 1M
    theta_loss_fused<<<blocks, 256, 0, stream>>>(theta4, affine4, cnt,
                                                 partial, out, n);
}

// Round 4
// 117.255 us; speedup vs baseline: 1.5872x; 1.5872x over previous
//
#include <hip/hip_runtime.h>
#include <math.h>

#define SUB 256          // samples per sub-tile (== blockDim)
#define SPB (2 * SUB)    // samples per block

// Ortho term for one sample. fp32 throughout EXCEPT detW (fp64): det has
// catastrophic cancellation (true value ~sigma1*sigma2*sigma3 << term
// magnitudes) and sigma_min feeds (sigma+eps)^-2 ~ 1e12 which dominates the
// loss. Error budget: sigma3 needs only ~0.4% REL accuracy once det is
// exact, so the fixed point / quadratic / sqrt can all be fp32.
__device__ __forceinline__ void sample_ortho(const float4 t0, const float4 t1,
                                             const float4 t2, double& ortho)
{
    float w00 = t0.x, w01 = t0.y, w02 = t0.z;
    float w10 = t1.x, w11 = t1.y, w12 = t1.z;
    float w20 = t2.x, w21 = t2.y, w22 = t2.z;

    // A = W^T W (fp32)
    float A00 = w00*w00 + w10*w10 + w20*w20;
    float A11 = w01*w01 + w11*w11 + w21*w21;
    float A22 = w02*w02 + w12*w12 + w22*w22;
    float A01 = w00*w01 + w10*w11 + w20*w21;
    float A02 = w00*w02 + w10*w12 + w20*w22;
    float A12 = w01*w02 + w11*w12 + w21*w22;

    float I1 = A00 + A11 + A22;
    float I2 = (A00*A11 - A01*A01) + (A00*A22 - A02*A02) + (A11*A22 - A12*A12);

    // det(W) in fp64 — the one cancellation-critical quantity.
    double dw = (double)w00 * ((double)w11 * (double)w22 - (double)w12 * (double)w21)
              - (double)w01 * ((double)w10 * (double)w22 - (double)w12 * (double)w20)
              + (double)w02 * ((double)w10 * (double)w21 - (double)w11 * (double)w20);
    float I3 = (float)(dw * dw);   // det(A) >= 0

    // Smallest eigenvalue: monotone fixed point lam <- I3 / q(lam),
    // q(lam) = lam^2 - I1*lam + I2. Converges from below; immediate for the
    // near-singular samples that dominate the loss.
    float lam = (I2 > 0.f) ? I3 / I2 : 0.f;
    #pragma unroll
    for (int it = 0; it < 6; ++it) {
        float q = (lam - I1) * lam + I2;
        lam = (q > 0.f) ? I3 / q : lam;
    }
    if (lam < 0.f) lam = 0.f;

    // Remaining two eigenvalues from the deflated quadratic.
    float S = I1 - lam;
    float P = (lam - I1) * lam + I2;    // ~ lam1*lam2
    float disc = S * S - 4.f * P;
    disc = (disc > 0.f) ? sqrtf(disc) : 0.f;
    float l1 = 0.5f * (S + disc); if (l1 < 0.f) l1 = 0.f;
    float l2 = 0.5f * (S - disc); if (l2 < 0.f) l2 = 0.f;

    float s1 = sqrtf(l1)  + 1e-6f;
    float s2 = sqrtf(l2)  + 1e-6f;
    float s3 = sqrtf(lam) + 1e-6f;
    float q1 = s1 * s1, q2 = s2 * s2, q3 = s3 * s3;
    float inv = 1.f / (q1 * q2 * q3);
    ortho += (double)((q1 + q2 + q3) + inv * (q2 * q3 + q1 * q3 + q1 * q2) - 6.f);
}

__global__ __launch_bounds__(256) void theta_loss_main(
    const float4* __restrict__ theta4,
    const float4* __restrict__ affine4,
    double* __restrict__ partial, int n)
{
    // 24 KB LDS: two 256-sample theta sub-tiles (affine never staged --
    // MSE is order-independent, accumulated during the coalesced pass).
    __shared__ float4 ldsA[3 * SUB];
    __shared__ float4 ldsB[3 * SUB];

    const int t = threadIdx.x;
    const int blockSample = blockIdx.x * SPB;
    const int n4 = n * 3;
    double mse = 0.0, ortho = 0.0;

    // ---- stage sub-tile 0 (coalesced float4) + streaming MSE ----
    {
        int base4 = blockSample * 3;
        #pragma unroll
        for (int k = 0; k < 3; ++k) {
            int j = base4 + t + k * SUB;
            float4 tv = make_float4(0.f, 0.f, 0.f, 0.f);
            float4 av = make_float4(0.f, 0.f, 0.f, 0.f);
            if (j < n4) { tv = theta4[j]; av = affine4[j]; }
            float dx = tv.x - av.x, dy = tv.y - av.y;
            float dz = tv.z - av.z, dw = tv.w - av.w;
            mse += (double)(dx * dx + dy * dy) + (double)(dz * dz + dw * dw);
            ldsA[t + k * SUB] = tv;
        }
    }
    __syncthreads();

    // ---- issue sub-tile-1 global loads early (overlap with compute 0) ----
    float4 tvB[3], avB[3];
    {
        int base4 = (blockSample + SUB) * 3;
        #pragma unroll
        for (int k = 0; k < 3; ++k) {
            int j = base4 + t + k * SUB;
            tvB[k] = make_float4(0.f, 0.f, 0.f, 0.f);
            avB[k] = make_float4(0.f, 0.f, 0.f, 0.f);
            if (j < n4) { tvB[k] = theta4[j]; avB[k] = affine4[j]; }
        }
    }

    // ---- compute sub-tile 0 (stride-12-dword LDS reads: conflict-free) ----
    if (blockSample + t < n) {
        float4 a0 = ldsA[3 * t], a1 = ldsA[3 * t + 1], a2 = ldsA[3 * t + 2];
        sample_ortho(a0, a1, a2, ortho);
    }

    // ---- finish staging sub-tile 1 ----
    #pragma unroll
    for (int k = 0; k < 3; ++k) {
        float dx = tvB[k].x - avB[k].x, dy = tvB[k].y - avB[k].y;
        float dz = tvB[k].z - avB[k].z, dw = tvB[k].w - avB[k].w;
        mse += (double)(dx * dx + dy * dy) + (double)(dz * dz + dw * dw);
        ldsB[t + k * SUB] = tvB[k];
    }
    __syncthreads();

    // ---- compute sub-tile 1 ----
    if (blockSample + SUB + t < n) {
        float4 b0 = ldsB[3 * t], b1 = ldsB[3 * t + 1], b2 = ldsB[3 * t + 2];
        sample_ortho(b0, b1, b2, ortho);
    }

    // ---- block reduction: wave64 shuffle -> LDS -> per-block partial ----
    #pragma unroll
    for (int off = 32; off > 0; off >>= 1) {
        ortho += __shfl_down(ortho, off);
        mse   += __shfl_down(mse, off);
    }
    __shared__ double so[4], sm[4];
    int lane = t & 63, wv = t >> 6;
    if (lane == 0) { so[wv] = ortho; sm[wv] = mse; }
    __syncthreads();
    if (t == 0) {
        partial[2 * blockIdx.x]     = so[0] + so[1] + so[2] + so[3];
        partial[2 * blockIdx.x + 1] = sm[0] + sm[1] + sm[2] + sm[3];
    }
}

__global__ __launch_bounds__(256) void finalize_out(
    const double* __restrict__ partial, float* __restrict__ out,
    int nblocks, int n)
{
    double O = 0.0, M = 0.0;
    for (int i = threadIdx.x; i < nblocks; i += 256) {
        O += partial[2 * i];
        M += partial[2 * i + 1];
    }
    #pragma unroll
    for (int off = 32; off > 0; off >>= 1) {
        O += __shfl_down(O, off);
        M += __shfl_down(M, off);
    }
    __shared__ double so[4], sm[4];
    int lane = threadIdx.x & 63, wv = threadIdx.x >> 6;
    if (lane == 0) { so[wv] = O; sm[wv] = M; }
    __syncthreads();
    if (threadIdx.x == 0) {
        double Ot = so[0] + so[1] + so[2] + so[3];
        double Mt = sm[0] + sm[1] + sm[2] + sm[3];
        out[0] = (float)(Ot / (double)n);
        out[1] = (float)(Mt / (12.0 * (double)n));
    }
}

extern "C" void kernel_launch(void* const* d_in, const int* in_sizes, int n_in,
                              void* d_out, int out_size, void* d_ws, size_t ws_size,
                              hipStream_t stream) {
    const float4* theta4  = (const float4*)d_in[0];
    const float4* affine4 = (const float4*)d_in[1];
    double* partial = (double*)d_ws;
    float* out = (float*)d_out;
    int n = in_sizes[0] / 12;           // samples of 3x4

    int blocks = (n + SPB - 1) / SPB;   // 2048 for n = 1M
    theta_loss_main<<<blocks, 256, 0, stream>>>(theta4, affine4, partial, n);
    finalize_out<<<1, 256, 0, stream>>>(partial, out, blocks, n);
}